// Round 5
// baseline (432.858 us; speedup 1.0000x reference)
//
#include <hip/hip_runtime.h>

// PhotometricLoss: fused warp + SSIM(3x3 avgpool, zero-pad) + L1 + masked mean.
// B=8, C=3, H=720, W=1280 fp32.
//
// R8: R7's shuffle-gather (proven: per-wave duty 11%->37%) with the VGPR
// explosion fixed. R7 post-mortem: manual prefetch + unbounded unroll let the
// compiler hoist loads across steps -> 172 VGPR -> 10.5% occupancy -> 147us.
// R4 post-mortem: VGPR_Count=52 proves the compiler SINKS prefetches when
// register-constrained -> source-level load placement is dead either way; the
// real knob is the register BUDGET. So:
//  1. No manual prefetch: per-step loads (disp,left x3, right-halo x6) are all
//     coalesced and address-independent -> compiler pipelines them itself.
//  2. 2-slot named stat ring (30 regs, was 45): emit center r-1 in the step
//     where row r's stats are born. Full unroll (rolled loops spill: R5/R6).
//  3. __launch_bounds__(256,4): 128-reg cap -> 4 waves/SIMD floor, caps the
//     hoisting appetite. Revert signal: WRITE_SIZE in MBs = spills.
// Gather stays register-resident: per channel two 64-wide clamped halo loads
// (window cols s0-8..s0+119), per-lane dynamic __shfl (ds_bpermute) + select.
// Border-exact via clamped halo addresses; window-miss (P~1e-11/px) takes an
// exact per-lane global fallback under __any.

#define P_ALPHA 0.85f
#define P_C1 1e-4f
#define P_C2 9e-4f

constexpr int COLS  = 62;   // useful output columns per wave strip
constexpr int RPW   = 15;   // output rows per wave (720 = 12*4*15)
constexpr int WAVES = 4;    // waves per block

__global__ __launch_bounds__(256, 4)
void photo_loss_kernel(const float* __restrict__ disp,
                       const float* __restrict__ left,
                       const float* __restrict__ right,
                       float* __restrict__ acc,   // acc[0]=sum(photo*valid), acc[1]=sum(valid)
                       int H, int W)
{
    __shared__ float redpv[WAVES];
    __shared__ float redv[WAVES];

    const int tid  = threadIdx.x;
    const int lane = tid & 63;
    const int w    = tid >> 6;
    const int b    = blockIdx.z;
    const int s0   = blockIdx.x * COLS;
    const int col  = s0 + lane - 1;                         // -1 .. W (+halo)
    const int rowStart = (blockIdx.y * WAVES + w) * RPW;

    const int planeHW = H * W;
    const float* __restrict__ dispb = disp  + b * planeHW;
    const float* __restrict__ L0 = left  + (b * 3 + 0) * planeHW;
    const float* __restrict__ L1 = left  + (b * 3 + 1) * planeHW;
    const float* __restrict__ L2 = left  + (b * 3 + 2) * planeHW;
    const float* __restrict__ R0 = right + (b * 3 + 0) * planeHW;
    const float* __restrict__ R1 = right + (b * 3 + 1) * planeHW;
    const float* __restrict__ R2 = right + (b * 3 + 2) * planeHW;

    const float wm1f = (float)(W - 1);
    const float colf = (float)col;
    const int   colC = min(max(col, 0), W - 1);             // clamped address col
    const float colv = (col >= 0 && col < W) ? 1.f : 0.f;   // column validity
    const float ocm  = (lane >= 1 && lane <= COLS && col < W) ? 1.f : 0.f;  // output mask

    // halo columns this lane provides (clamped -> border-exact window values)
    const int colA = min(max(s0 - 8  + lane, 0), W - 1);    // window idx 0..63  = cols s0-8 .. s0+55
    const int colB = min(max(s0 + 56 + lane, 0), W - 1);    // window idx 64..127 = cols s0+56 .. s0+119

    // 2-slot named stat ring: A = h[r-2], B = h[r-1]
    float Ax0=0.f,Ay0=0.f,Axx0=0.f,Ayy0=0.f,Axy0=0.f;
    float Ax1=0.f,Ay1=0.f,Axx1=0.f,Ayy1=0.f,Axy1=0.f;
    float Ax2=0.f,Ay2=0.f,Axx2=0.f,Ayy2=0.f,Axy2=0.f;
    float Bx0=0.f,By0=0.f,Bxx0=0.f,Byy0=0.f,Bxy0=0.f;
    float Bx1=0.f,By1=0.f,Bxx1=0.f,Byy1=0.f,Bxy1=0.f;
    float Bx2=0.f,By2=0.f,Bxx2=0.f,Byy2=0.f,Bxy2=0.f;
    float l1B=0.f, vB=0.f;                  // l1/valid of the row held in B

    float sum_pv = 0.f, sum_v = 0.f;

    #pragma unroll
    for (int j = 0; j < RPW + 2; ++j) {
        const int r  = rowStart - 1 + j;                    // row processed this step
        const int rc = min(max(r, 0), H - 1);
        const float rv = (r >= 0 && r < H) ? 1.f : 0.f;

        // ---- this row's loads: all coalesced, all address-independent ----
        const int   off = rc * W + colC;
        const float d   = dispb[off];
        const float xc0 = L0[off], xc1 = L1[off], xc2 = L2[off];
        const int   ro  = rc * W;
        const float hA0 = R0[ro + colA], hB0 = R0[ro + colB];
        const float hA1 = R1[ro + colA], hB1 = R1[ro + colB];
        const float hA2 = R2[ro + colA], hB2 = R2[ro + colB];

        // ---- register gather via dynamic shuffle ----
        const float xs  = colf - d;
        const float xcl = fminf(fmaxf(xs, 0.f), wm1f);
        const float xf  = floorf(xcl);
        const float fr  = xcl - xf;
        const int   i0  = (int)xf;
        const int   k   = i0 - s0 + 8;       // index into 128-col window
        const int   k1  = k + 1;
        const int   ks  = k & 63;
        const int   k1s = k1 & 63;
        float g00, g01, g10, g11, g20, g21;
        {
            const float a  = __shfl(hA0, ks, 64),  bb = __shfl(hB0, ks, 64);
            const float a1 = __shfl(hA0, k1s, 64), b1 = __shfl(hB0, k1s, 64);
            g00 = (k  < 64) ? a  : bb;
            g01 = (k1 < 64) ? a1 : b1;
        }
        {
            const float a  = __shfl(hA1, ks, 64),  bb = __shfl(hB1, ks, 64);
            const float a1 = __shfl(hA1, k1s, 64), b1 = __shfl(hB1, k1s, 64);
            g10 = (k  < 64) ? a  : bb;
            g11 = (k1 < 64) ? a1 : b1;
        }
        {
            const float a  = __shfl(hA2, ks, 64),  bb = __shfl(hB2, ks, 64);
            const float a1 = __shfl(hA2, k1s, 64), b1 = __shfl(hB2, k1s, 64);
            g20 = (k  < 64) ? a  : bb;
            g21 = (k1 < 64) ? a1 : b1;
        }
        // window miss (|disp| > ~70): exact per-lane global fallback, ~never taken
        const bool bad = (k < 0) || (k1 > 127);
        if (__builtin_expect(__any(bad), 0)) {
            if (bad) {
                const int i1 = min(i0 + 1, W - 1);
                g00 = R0[ro + i0]; g01 = R0[ro + i1];
                g10 = R1[ro + i0]; g11 = R1[ro + i1];
                g20 = R2[ro + i0]; g21 = R2[ro + i1];
            }
        }

        // ---- row-r values + horizontal stats (C) ----
        const float m   = rv * colv;
        const float omf = 1.f - fr;
        const float y0 = (omf * g00 + fr * g01) * m;
        const float y1 = (omf * g10 + fr * g11) * m;
        const float y2 = (omf * g20 + fr * g21) * m;
        const float x0 = xc0 * m;
        const float x1 = xc1 * m;
        const float x2 = xc2 * m;

        float Cx0,Cy0,Cxx0,Cyy0,Cxy0;
        float Cx1,Cy1,Cxx1,Cyy1,Cxy1;
        float Cx2,Cy2,Cxx2,Cyy2,Cxy2;
        {
            const float xl = __shfl_up(x0,1,64), xr = __shfl_down(x0,1,64);
            const float yl = __shfl_up(y0,1,64), yr = __shfl_down(y0,1,64);
            Cx0  = xl + x0 + xr;
            Cy0  = yl + y0 + yr;
            Cxx0 = xl*xl + x0*x0 + xr*xr;
            Cyy0 = yl*yl + y0*y0 + yr*yr;
            Cxy0 = xl*yl + x0*y0 + xr*yr;
        }
        {
            const float xl = __shfl_up(x1,1,64), xr = __shfl_down(x1,1,64);
            const float yl = __shfl_up(y1,1,64), yr = __shfl_down(y1,1,64);
            Cx1  = xl + x1 + xr;
            Cy1  = yl + y1 + yr;
            Cxx1 = xl*xl + x1*x1 + xr*xr;
            Cyy1 = yl*yl + y1*y1 + yr*yr;
            Cxy1 = xl*yl + x1*y1 + xr*yr;
        }
        {
            const float xl = __shfl_up(x2,1,64), xr = __shfl_down(x2,1,64);
            const float yl = __shfl_up(y2,1,64), yr = __shfl_down(y2,1,64);
            Cx2  = xl + x2 + xr;
            Cy2  = yl + y2 + yr;
            Cxx2 = xl*xl + x2*x2 + xr*xr;
            Cyy2 = yl*yl + y2*y2 + yr*yr;
            Cxy2 = xl*yl + x2*y2 + xr*yr;
        }
        const float l1C = fabsf(x0 - y0) + fabsf(x1 - y1) + fabsf(x2 - y2);
        const float vC  = (xs > 0.f && xs < wm1f) ? 1.f : 0.f;

        // ---- emit center r-1 using (A=h[r-2], B=h[r-1], C=h[r]) ----
        if (j >= 2) {                                       // compile-time after unroll
            const float inv9 = 1.f / 9.f;
            float ssim_sum = 0.f;
            #define SSIM_CH(SX,SY,SXX,SYY,SXY)                                   \
            {                                                                    \
                const float mu_x = (A##SX + B##SX + C##SX) * inv9;               \
                const float mu_y = (A##SY + B##SY + C##SY) * inv9;               \
                const float exx  = (A##SXX + B##SXX + C##SXX) * inv9;            \
                const float eyy  = (A##SYY + B##SYY + C##SYY) * inv9;            \
                const float exy  = (A##SXY + B##SXY + C##SXY) * inv9;            \
                const float sig_x  = fmaxf(exx - mu_x * mu_x, 0.f);              \
                const float sig_y  = fmaxf(eyy - mu_y * mu_y, 0.f);              \
                const float sig_xy = exy - mu_x * mu_y;                          \
                const float n  = (2.f*mu_x*mu_y + P_C1) * (2.f*sig_xy + P_C2);   \
                const float dd = (mu_x*mu_x + mu_y*mu_y + P_C1)                  \
                               * (sig_x + sig_y + P_C2);                         \
                float s = (1.f - n * __builtin_amdgcn_rcpf(dd)) * 0.5f;          \
                s = fminf(fmaxf(s, 0.f), 1.f);                                   \
                ssim_sum += s;                                                   \
            }
            SSIM_CH(x0,y0,xx0,yy0,xy0)
            SSIM_CH(x1,y1,xx1,yy1,xy1)
            SSIM_CH(x2,y2,xx2,yy2,xy2)
            #undef SSIM_CH
            const float photo = P_ALPHA * (ssim_sum * (1.f / 3.f))
                              + (1.f - P_ALPHA) * (l1B * (1.f / 3.f));
            sum_pv += photo * vB * ocm;
            sum_v  += vB * ocm;
        }

        // ---- ring shift (pure renames under full unroll) ----
        Ax0=Bx0; Ay0=By0; Axx0=Bxx0; Ayy0=Byy0; Axy0=Bxy0;
        Ax1=Bx1; Ay1=By1; Axx1=Bxx1; Ayy1=Byy1; Axy1=Bxy1;
        Ax2=Bx2; Ay2=By2; Axx2=Bxx2; Ayy2=Byy2; Axy2=Bxy2;
        Bx0=Cx0; By0=Cy0; Bxx0=Cxx0; Byy0=Cyy0; Bxy0=Cxy0;
        Bx1=Cx1; By1=Cy1; Bxx1=Cxx1; Byy1=Cyy1; Bxy1=Cxy1;
        Bx2=Cx2; By2=Cy2; Bxx2=Cxx2; Byy2=Cyy2; Bxy2=Cxy2;
        l1B = l1C; vB = vC;
    }

    // wave reduce (64 lanes) then cross-wave via tiny LDS
    #pragma unroll
    for (int off = 32; off > 0; off >>= 1) {
        sum_pv += __shfl_down(sum_pv, off, 64);
        sum_v  += __shfl_down(sum_v,  off, 64);
    }
    if (lane == 0) { redpv[w] = sum_pv; redv[w] = sum_v; }
    __syncthreads();
    if (tid == 0) {
        atomicAdd(&acc[0], redpv[0] + redpv[1] + redpv[2] + redpv[3]);
        atomicAdd(&acc[1], redv[0]  + redv[1]  + redv[2]  + redv[3]);
    }
}

__global__ void photo_loss_finalize(const float* __restrict__ acc,
                                    float* __restrict__ out)
{
    out[0] = acc[0] / fmaxf(acc[1], 1.f);
}

extern "C" void kernel_launch(void* const* d_in, const int* in_sizes, int n_in,
                              void* d_out, int out_size, void* d_ws, size_t ws_size,
                              hipStream_t stream)
{
    const float* disp  = (const float*)d_in[0];
    const float* left  = (const float*)d_in[1];
    const float* right = (const float*)d_in[2];
    float* out = (float*)d_out;
    float* acc = (float*)d_ws;

    const int B = 8, H = 720, W = 1280;

    hipMemsetAsync(acc, 0, 2 * sizeof(float), stream);

    // x: 21 strips of 62 cols; y: 720 / (4 waves * 15 rows) = 12; z: batch
    dim3 grid((W + COLS - 1) / COLS, H / (WAVES * RPW), B);
    dim3 block(256);
    photo_loss_kernel<<<grid, block, 0, stream>>>(disp, left, right, acc, H, W);
    photo_loss_finalize<<<1, 1, 0, stream>>>(acc, out);
}

// Round 6
// 333.728 us; speedup vs baseline: 1.2970x; 1.2970x over previous
//
#include <hip/hip_runtime.h>

// PhotometricLoss: fused warp + SSIM(3x3 avgpool, zero-pad) + L1 + masked mean.
// B=8, C=3, H=720, W=1280 fp32.
//
// R9: shuffle-gather + per-step sched_barrier(0), no launch_bounds.
// Session law (R3..R8): with the shuffle-gather structure every load is
// address-independent -> the compiler hoists loads across ALL unrolled steps:
//   no cap  -> 172 VGPR, occupancy 10% (R7, 147us)
//   cap 128 -> appetite 170 >> cap -> 437MB scratch spill (R8, 299us)
// launch_bounds is the wrong knob (register cliff). The right knob is the
// scheduler's MOTION RANGE: __builtin_amdgcn_sched_barrier(0) at each step
// boundary forbids cross-step hoisting -> live state = ring(34) + in-step
// transients (~40) ~= 70-90 VGPR, no cap to spill against (default budget).
// Per-wave duty ~30% (360 issue-cyc vs ~900cyc HBM latency per step) x 5-7
// resident waves/SIMD -> issue-saturated. Floors: VALU ~25us, HBM ~35us.
// Gather (unchanged, proven): per channel two 64-wide clamped coalesced halo
// loads (window cols s0-8..s0+119); per-lane dynamic __shfl + select;
// border-exact via clamped halo addresses; window-miss (P~1e-11/px) takes an
// exact per-lane global fallback under __any. absmax=0 in R7/R8.

#define P_ALPHA 0.85f
#define P_C1 1e-4f
#define P_C2 9e-4f

constexpr int COLS  = 62;   // useful output columns per wave strip
constexpr int RPW   = 15;   // output rows per wave (720 = 12*4*15)
constexpr int WAVES = 4;    // waves per block

__global__ __launch_bounds__(256)
void photo_loss_kernel(const float* __restrict__ disp,
                       const float* __restrict__ left,
                       const float* __restrict__ right,
                       float* __restrict__ acc,   // acc[0]=sum(photo*valid), acc[1]=sum(valid)
                       int H, int W)
{
    __shared__ float redpv[WAVES];
    __shared__ float redv[WAVES];

    const int tid  = threadIdx.x;
    const int lane = tid & 63;
    const int w    = tid >> 6;
    const int b    = blockIdx.z;
    const int s0   = blockIdx.x * COLS;
    const int col  = s0 + lane - 1;                         // -1 .. W (+halo)
    const int rowStart = (blockIdx.y * WAVES + w) * RPW;

    const int planeHW = H * W;
    const float* __restrict__ dispb = disp  + b * planeHW;
    const float* __restrict__ L0 = left  + (b * 3 + 0) * planeHW;
    const float* __restrict__ L1 = left  + (b * 3 + 1) * planeHW;
    const float* __restrict__ L2 = left  + (b * 3 + 2) * planeHW;
    const float* __restrict__ R0 = right + (b * 3 + 0) * planeHW;
    const float* __restrict__ R1 = right + (b * 3 + 1) * planeHW;
    const float* __restrict__ R2 = right + (b * 3 + 2) * planeHW;

    const float wm1f = (float)(W - 1);
    const float colf = (float)col;
    const int   colC = min(max(col, 0), W - 1);             // clamped address col
    const float colv = (col >= 0 && col < W) ? 1.f : 0.f;   // column validity
    const float ocm  = (lane >= 1 && lane <= COLS && col < W) ? 1.f : 0.f;  // output mask

    // halo columns this lane provides (clamped -> border-exact window values)
    const int colA = min(max(s0 - 8  + lane, 0), W - 1);    // window idx 0..63   = cols s0-8 .. s0+55
    const int colB = min(max(s0 + 56 + lane, 0), W - 1);    // window idx 64..127 = cols s0+56 .. s0+119

    // 2-slot named stat ring: A = h[r-2], B = h[r-1]
    float Ax0=0.f,Ay0=0.f,Axx0=0.f,Ayy0=0.f,Axy0=0.f;
    float Ax1=0.f,Ay1=0.f,Axx1=0.f,Ayy1=0.f,Axy1=0.f;
    float Ax2=0.f,Ay2=0.f,Axx2=0.f,Ayy2=0.f,Axy2=0.f;
    float Bx0=0.f,By0=0.f,Bxx0=0.f,Byy0=0.f,Bxy0=0.f;
    float Bx1=0.f,By1=0.f,Bxx1=0.f,Byy1=0.f,Bxy1=0.f;
    float Bx2=0.f,By2=0.f,Bxx2=0.f,Byy2=0.f,Bxy2=0.f;
    float l1B=0.f, vB=0.f;                  // l1/valid of the row held in B

    float sum_pv = 0.f, sum_v = 0.f;

    #pragma unroll
    for (int j = 0; j < RPW + 2; ++j) {
        // forbid cross-step code motion: caps hoisting-driven register bloat
        __builtin_amdgcn_sched_barrier(0);

        const int r  = rowStart - 1 + j;                    // row processed this step
        const int rc = min(max(r, 0), H - 1);
        const float rv = (r >= 0 && r < H) ? 1.f : 0.f;

        // ---- this row's loads: all coalesced, all address-independent ----
        const int   off = rc * W + colC;
        const float d   = dispb[off];
        const float xc0 = L0[off], xc1 = L1[off], xc2 = L2[off];
        const int   ro  = rc * W;
        const float hA0 = R0[ro + colA], hB0 = R0[ro + colB];
        const float hA1 = R1[ro + colA], hB1 = R1[ro + colB];
        const float hA2 = R2[ro + colA], hB2 = R2[ro + colB];

        // ---- register gather via dynamic shuffle ----
        const float xs  = colf - d;
        const float xcl = fminf(fmaxf(xs, 0.f), wm1f);
        const float xf  = floorf(xcl);
        const float fr  = xcl - xf;
        const int   i0  = (int)xf;
        const int   k   = i0 - s0 + 8;       // index into 128-col window
        const int   k1  = k + 1;
        const int   ks  = k & 63;
        const int   k1s = k1 & 63;
        float g00, g01, g10, g11, g20, g21;
        {
            const float a  = __shfl(hA0, ks, 64),  bb = __shfl(hB0, ks, 64);
            const float a1 = __shfl(hA0, k1s, 64), b1 = __shfl(hB0, k1s, 64);
            g00 = (k  < 64) ? a  : bb;
            g01 = (k1 < 64) ? a1 : b1;
        }
        {
            const float a  = __shfl(hA1, ks, 64),  bb = __shfl(hB1, ks, 64);
            const float a1 = __shfl(hA1, k1s, 64), b1 = __shfl(hB1, k1s, 64);
            g10 = (k  < 64) ? a  : bb;
            g11 = (k1 < 64) ? a1 : b1;
        }
        {
            const float a  = __shfl(hA2, ks, 64),  bb = __shfl(hB2, ks, 64);
            const float a1 = __shfl(hA2, k1s, 64), b1 = __shfl(hB2, k1s, 64);
            g20 = (k  < 64) ? a  : bb;
            g21 = (k1 < 64) ? a1 : b1;
        }
        // window miss (|disp| > ~70): exact per-lane global fallback, ~never taken
        const bool bad = (k < 0) || (k1 > 127);
        if (__builtin_expect(__any(bad), 0)) {
            if (bad) {
                const int i1 = min(i0 + 1, W - 1);
                g00 = R0[ro + i0]; g01 = R0[ro + i1];
                g10 = R1[ro + i0]; g11 = R1[ro + i1];
                g20 = R2[ro + i0]; g21 = R2[ro + i1];
            }
        }

        // ---- row-r values + horizontal stats (C) ----
        const float m   = rv * colv;
        const float omf = 1.f - fr;
        const float y0 = (omf * g00 + fr * g01) * m;
        const float y1 = (omf * g10 + fr * g11) * m;
        const float y2 = (omf * g20 + fr * g21) * m;
        const float x0 = xc0 * m;
        const float x1 = xc1 * m;
        const float x2 = xc2 * m;

        float Cx0,Cy0,Cxx0,Cyy0,Cxy0;
        float Cx1,Cy1,Cxx1,Cyy1,Cxy1;
        float Cx2,Cy2,Cxx2,Cyy2,Cxy2;
        {
            const float xl = __shfl_up(x0,1,64), xr = __shfl_down(x0,1,64);
            const float yl = __shfl_up(y0,1,64), yr = __shfl_down(y0,1,64);
            Cx0  = xl + x0 + xr;
            Cy0  = yl + y0 + yr;
            Cxx0 = xl*xl + x0*x0 + xr*xr;
            Cyy0 = yl*yl + y0*y0 + yr*yr;
            Cxy0 = xl*yl + x0*y0 + xr*yr;
        }
        {
            const float xl = __shfl_up(x1,1,64), xr = __shfl_down(x1,1,64);
            const float yl = __shfl_up(y1,1,64), yr = __shfl_down(y1,1,64);
            Cx1  = xl + x1 + xr;
            Cy1  = yl + y1 + yr;
            Cxx1 = xl*xl + x1*x1 + xr*xr;
            Cyy1 = yl*yl + y1*y1 + yr*yr;
            Cxy1 = xl*yl + x1*y1 + xr*yr;
        }
        {
            const float xl = __shfl_up(x2,1,64), xr = __shfl_down(x2,1,64);
            const float yl = __shfl_up(y2,1,64), yr = __shfl_down(y2,1,64);
            Cx2  = xl + x2 + xr;
            Cy2  = yl + y2 + yr;
            Cxx2 = xl*xl + x2*x2 + xr*xr;
            Cyy2 = yl*yl + y2*y2 + yr*yr;
            Cxy2 = xl*yl + x2*y2 + xr*yr;
        }
        const float l1C = fabsf(x0 - y0) + fabsf(x1 - y1) + fabsf(x2 - y2);
        const float vC  = (xs > 0.f && xs < wm1f) ? 1.f : 0.f;

        // ---- emit center r-1 using (A=h[r-2], B=h[r-1], C=h[r]) ----
        if (j >= 2) {                                       // compile-time after unroll
            const float inv9 = 1.f / 9.f;
            float ssim_sum = 0.f;
            #define SSIM_CH(SX,SY,SXX,SYY,SXY)                                   \
            {                                                                    \
                const float mu_x = (A##SX + B##SX + C##SX) * inv9;               \
                const float mu_y = (A##SY + B##SY + C##SY) * inv9;               \
                const float exx  = (A##SXX + B##SXX + C##SXX) * inv9;            \
                const float eyy  = (A##SYY + B##SYY + C##SYY) * inv9;            \
                const float exy  = (A##SXY + B##SXY + C##SXY) * inv9;            \
                const float sig_x  = fmaxf(exx - mu_x * mu_x, 0.f);              \
                const float sig_y  = fmaxf(eyy - mu_y * mu_y, 0.f);              \
                const float sig_xy = exy - mu_x * mu_y;                          \
                const float n  = (2.f*mu_x*mu_y + P_C1) * (2.f*sig_xy + P_C2);   \
                const float dd = (mu_x*mu_x + mu_y*mu_y + P_C1)                  \
                               * (sig_x + sig_y + P_C2);                         \
                float s = (1.f - n * __builtin_amdgcn_rcpf(dd)) * 0.5f;          \
                s = fminf(fmaxf(s, 0.f), 1.f);                                   \
                ssim_sum += s;                                                   \
            }
            SSIM_CH(x0,y0,xx0,yy0,xy0)
            SSIM_CH(x1,y1,xx1,yy1,xy1)
            SSIM_CH(x2,y2,xx2,yy2,xy2)
            #undef SSIM_CH
            const float photo = P_ALPHA * (ssim_sum * (1.f / 3.f))
                              + (1.f - P_ALPHA) * (l1B * (1.f / 3.f));
            sum_pv += photo * vB * ocm;
            sum_v  += vB * ocm;
        }

        // ---- ring shift (pure renames under full unroll) ----
        Ax0=Bx0; Ay0=By0; Axx0=Bxx0; Ayy0=Byy0; Axy0=Bxy0;
        Ax1=Bx1; Ay1=By1; Axx1=Bxx1; Ayy1=Byy1; Axy1=Bxy1;
        Ax2=Bx2; Ay2=By2; Axx2=Bxx2; Ayy2=Byy2; Axy2=Bxy2;
        Bx0=Cx0; By0=Cy0; Bxx0=Cxx0; Byy0=Cyy0; Bxy0=Cxy0;
        Bx1=Cx1; By1=Cy1; Bxx1=Cxx1; Byy1=Cyy1; Bxy1=Cxy1;
        Bx2=Cx2; By2=Cy2; Bxx2=Cxx2; Byy2=Cyy2; Bxy2=Cxy2;
        l1B = l1C; vB = vC;
    }

    // wave reduce (64 lanes) then cross-wave via tiny LDS
    #pragma unroll
    for (int off = 32; off > 0; off >>= 1) {
        sum_pv += __shfl_down(sum_pv, off, 64);
        sum_v  += __shfl_down(sum_v,  off, 64);
    }
    if (lane == 0) { redpv[w] = sum_pv; redv[w] = sum_v; }
    __syncthreads();
    if (tid == 0) {
        atomicAdd(&acc[0], redpv[0] + redpv[1] + redpv[2] + redpv[3]);
        atomicAdd(&acc[1], redv[0]  + redv[1]  + redv[2]  + redv[3]);
    }
}

__global__ void photo_loss_finalize(const float* __restrict__ acc,
                                    float* __restrict__ out)
{
    out[0] = acc[0] / fmaxf(acc[1], 1.f);
}

extern "C" void kernel_launch(void* const* d_in, const int* in_sizes, int n_in,
                              void* d_out, int out_size, void* d_ws, size_t ws_size,
                              hipStream_t stream)
{
    const float* disp  = (const float*)d_in[0];
    const float* left  = (const float*)d_in[1];
    const float* right = (const float*)d_in[2];
    float* out = (float*)d_out;
    float* acc = (float*)d_ws;

    const int B = 8, H = 720, W = 1280;

    hipMemsetAsync(acc, 0, 2 * sizeof(float), stream);

    // x: 21 strips of 62 cols; y: 720 / (4 waves * 15 rows) = 12; z: batch
    dim3 grid((W + COLS - 1) / COLS, H / (WAVES * RPW), B);
    dim3 block(256);
    photo_loss_kernel<<<grid, block, 0, stream>>>(disp, left, right, acc, H, W);
    photo_loss_finalize<<<1, 1, 0, stream>>>(acc, out);
}